// Round 11
// baseline (271.456 us; speedup 1.0000x reference)
//
#include <hip/hip_runtime.h>
#include <stdint.h>

#define EMBED 1024
#define SEQ   2048
#define BATCH 4
#define HEADS 16
#define HDIM  64
#define LDP   72   // transpose_v LDS stride

typedef unsigned short ushort_t;
typedef __bf16 bf16x8 __attribute__((ext_vector_type(8)));
typedef __bf16 bf16x4 __attribute__((ext_vector_type(4)));
typedef float  f32x4  __attribute__((ext_vector_type(4)));
typedef float  f32x16 __attribute__((ext_vector_type(16)));

#define MFMA16 __builtin_amdgcn_mfma_f32_16x16x32_bf16
#define MFMA32 __builtin_amdgcn_mfma_f32_32x32x16_bf16

typedef __attribute__((address_space(3))) uint32_t lds_u32_t;
typedef __attribute__((address_space(1))) const uint32_t glb_u32_t;

// async global->LDS, 16 B/lane; LDS dest = wave-uniform base + lane*16 (m97/m104)
__device__ __forceinline__ void gl_lds16(const ushort_t* g, ushort_t* l) {
    __builtin_amdgcn_global_load_lds((glb_u32_t*)g, (lds_u32_t*)l, 16, 0, 0);
}

__device__ __forceinline__ ushort_t f2bf(float f) {
    union { float f; uint32_t u; } c; c.f = f;
    uint32_t u = c.u;
    return (ushort_t)((u + 0x7FFFu + ((u >> 16) & 1u)) >> 16);
}

// v_exp_f32 computes 2^x; log2(e) is folded into the Q scale in gemm_qkv
__device__ __forceinline__ float exp2f_fast(float x) {
    float r; asm("v_exp_f32 %0, %1" : "=v"(r) : "v"(x)); return r;
}

// ------- prep: cast x (blocks 0..4095) + cast/transpose 4 W (blocks 4096..5119) -------
__global__ __launch_bounds__(256)
void prep(const float* __restrict__ X, ushort_t* __restrict__ Xb,
          const float* __restrict__ W0, const float* __restrict__ W1,
          const float* __restrict__ W2, const float* __restrict__ W3,
          ushort_t* __restrict__ WtAll)
{
    __shared__ ushort_t Ts[64 * 80];
    const int t = threadIdx.x;
    if (blockIdx.x < 4096) {
        size_t i = ((size_t)blockIdx.x * 256 + t) * 8;
        ushort_t tmp[8];
        #pragma unroll
        for (int e = 0; e < 8; ++e) tmp[e] = f2bf(X[i + e]);
        *(uint4*)(Xb + i) = *(const uint4*)tmp;
        return;
    }
    const int rb = blockIdx.x - 4096;            // 0..1023
    const int z = rb >> 8, rem = rb & 255;
    const float* W = (z == 0) ? W0 : (z == 1) ? W1 : (z == 2) ? W2 : W3;
    ushort_t* Wt = WtAll + (size_t)z * EMBED * EMBED;
    const int k0 = (rem & 15) * 64, n0 = (rem >> 4) * 64;
    const int r = t >> 2, cs = (t & 3) * 16;
    const float* src = W + (size_t)(k0 + r) * EMBED + n0 + cs;
    #pragma unroll
    for (int e = 0; e < 16; ++e) Ts[(cs + e) * 80 + r] = f2bf(src[e]);
    __syncthreads();
    const int n = t >> 2, ks = (t & 3) * 16;
    ushort_t* dst = Wt + (size_t)(n0 + n) * EMBED + k0 + ks;
    *(uint4*)(dst)     = *(const uint4*)(&Ts[n * 80 + ks]);
    *(uint4*)(dst + 8) = *(const uint4*)(&Ts[n * 80 + ks + 8]);
}

// ---------------- merged QKV GEMM: [8192,3072] = xb @ WtQKV^T + bias ----------------
// m97-sync structure, 256x128 tile (R11): 512 threads, 8 waves in 4Mx2N grid, each wave
// the same verified 64x64 acc[4][4]. BK=32, global_load_lds width-16, 2-barrier K-loop.
// vs 128x128: staged L2 traffic -25% (768 blocks x 768KB vs 1536 x 512KB), VGPR ~80 ->
// 6 waves/SIMD -> 3 blocks x 8 waves = 24 waves/CU, grid 768 = 3x256 exact (no tail).
__global__ __launch_bounds__(512)
void gemm_qkv(const ushort_t* __restrict__ A, const ushort_t* __restrict__ Bt,
              const float* __restrict__ bq, const float* __restrict__ bk,
              const float* __restrict__ bv, ushort_t* __restrict__ Cq, size_t tsz)
{
    __shared__ ushort_t As[256 * 32];   // [m][k], unpadded (required by global_load_lds)
    __shared__ ushort_t Bs[128 * 32];   // [n][k]
    const int t = threadIdx.x;
    const int wave = t >> 6, lane = t & 63;
    const int l15 = lane & 15, quad = lane >> 4;
    const int m0 = blockIdx.y * 256, n0 = blockIdx.x * 128;
    const int wm = (wave >> 1) * 64, wn = (wave & 1) * 64;
    f32x4 acc[4][4] = {};

    // staging: 512 threads cover 128 rows x 32 cols per issue; A = 2 issues, B = 1
    const int srow = t >> 2, scol = (t & 3) * 8;
    const ushort_t* Ag = A  + (size_t)(m0 + srow) * EMBED + scol;
    const ushort_t* Bg = Bt + (size_t)(n0 + srow) * EMBED + scol;
    ushort_t* AsW = As + wave * 512;             // wave-uniform LDS base (16 rows/wave)
    ushort_t* BsW = Bs + wave * 512;

    for (int k0 = 0; k0 < EMBED; k0 += 32) {
        gl_lds16(Ag + k0,               AsW);
        gl_lds16(Ag + k0 + 128 * EMBED, AsW + 4096);   // rows 128..255
        gl_lds16(Bg + k0,               BsW);
        __syncthreads();

        bf16x8 af[4], bfr[4];
        #pragma unroll
        for (int mt = 0; mt < 4; ++mt)
            af[mt] = *(const bf16x8*)(&As[(wm + mt * 16 + l15) * 32 + quad * 8]);
        #pragma unroll
        for (int nt = 0; nt < 4; ++nt)
            bfr[nt] = *(const bf16x8*)(&Bs[(wn + nt * 16 + l15) * 32 + quad * 8]);
        #pragma unroll
        for (int mt = 0; mt < 4; ++mt)
            #pragma unroll
            for (int nt = 0; nt < 4; ++nt)
                acc[mt][nt] = MFMA16(af[mt], bfr[nt], acc[mt][nt], 0, 0, 0);
        __syncthreads();
    }

    const int mat = blockIdx.x >> 3;
    const float* bias = (mat == 0) ? bq : (mat == 1) ? bk : bv;
    // Q scale = 1/sqrt(64) * log2(e): flash uses v_exp_f32 (2^x) directly
    const float scale = (mat == 0) ? 0.18033688011112042f : 1.0f;
    ushort_t* C = Cq + (size_t)mat * tsz;
    const int nc0 = (blockIdx.x & 7) * 128;
    #pragma unroll
    for (int nt = 0; nt < 4; ++nt) {
        int col = nc0 + wn + nt * 16 + l15;
        float bb = bias[col];
        #pragma unroll
        for (int mt = 0; mt < 4; ++mt)
            #pragma unroll
            for (int r = 0; r < 4; ++r) {
                int row = m0 + wm + mt * 16 + quad * 4 + r;
                C[(size_t)row * EMBED + col] = f2bf((acc[mt][nt][r] + bb) * scale);
            }
    }
}

// ---------------- O-projection GEMM: out[8192,1024] fp32 = Ob @ Wt3^T + bo ----------------
// 8-wave 512-thread variant (verified R10): 128x128 tile, waves 2x4 each 64x32.
__global__ __launch_bounds__(512)
void gemm_o(const ushort_t* __restrict__ A, const ushort_t* __restrict__ Bt,
            const float* __restrict__ bias, float* __restrict__ C)
{
    __shared__ ushort_t As[128 * 32];
    __shared__ ushort_t Bs[128 * 32];
    const int t = threadIdx.x;
    const int wave = t >> 6, lane = t & 63;
    const int l15 = lane & 15, quad = lane >> 4;
    const int m0 = blockIdx.y * 128, n0 = blockIdx.x * 128;
    const int wmi = wave >> 2, wni = wave & 3;   // 2x4 wave grid: 64 rows x 32 cols each
    f32x4 acc[4][2] = {};

    const int srow = t >> 2, scol = (t & 3) * 8; // 512 threads cover 128x32 in one issue
    const ushort_t* Ag = A  + (size_t)(m0 + srow) * EMBED + scol;
    const ushort_t* Bg = Bt + (size_t)(n0 + srow) * EMBED + scol;
    ushort_t* AsW = As + wave * 512;             // 16 rows x 32 cols per wave
    ushort_t* BsW = Bs + wave * 512;

    for (int k0 = 0; k0 < EMBED; k0 += 32) {
        gl_lds16(Ag + k0, AsW);
        gl_lds16(Bg + k0, BsW);
        __syncthreads();

        bf16x8 af[4], bfr[2];
        #pragma unroll
        for (int mt = 0; mt < 4; ++mt)
            af[mt] = *(const bf16x8*)(&As[(wmi * 64 + mt * 16 + l15) * 32 + quad * 8]);
        #pragma unroll
        for (int nt = 0; nt < 2; ++nt)
            bfr[nt] = *(const bf16x8*)(&Bs[(wni * 32 + nt * 16 + l15) * 32 + quad * 8]);
        #pragma unroll
        for (int mt = 0; mt < 4; ++mt)
            #pragma unroll
            for (int nt = 0; nt < 2; ++nt)
                acc[mt][nt] = MFMA16(af[mt], bfr[nt], acc[mt][nt], 0, 0, 0);
        __syncthreads();
    }

    #pragma unroll
    for (int nt = 0; nt < 2; ++nt) {
        int col = n0 + wni * 32 + nt * 16 + l15;
        float bb = bias[col];
        #pragma unroll
        for (int mt = 0; mt < 4; ++mt)
            #pragma unroll
            for (int r = 0; r < 4; ++r) {
                int row = m0 + wmi * 64 + mt * 16 + quad * 4 + r;
                C[(size_t)row * EMBED + col] = acc[mt][nt][r] + bb;
            }
    }
}

// ---------------- V transpose: V[B,S,E] -> Vt[(b*H+h)*64+d][s] ----------------
__global__ __launch_bounds__(256)
void transpose_v(const ushort_t* __restrict__ V, ushort_t* __restrict__ Vt)
{
    int blk = blockIdx.x;
    int st = blk & 31, bh = blk >> 5;
    int h = bh & 15, b = bh >> 4;
    int s0 = st * 64;
    __shared__ ushort_t Ts[64 * LDP];
    int tid = threadIdx.x;
    int r = tid >> 2, g = (tid & 3) * 8;

    const ushort_t* src = V + ((size_t)(b * SEQ + s0 + r)) * EMBED + h * HDIM;
    uint4 v0 = *(const uint4*)(src + g);
    uint4 v1 = *(const uint4*)(src + g + 32);
    const ushort_t* e0 = (const ushort_t*)&v0;
    const ushort_t* e1 = (const ushort_t*)&v1;
    #pragma unroll
    for (int e = 0; e < 8; ++e) Ts[(g + e) * LDP + r] = e0[e];
    #pragma unroll
    for (int e = 0; e < 8; ++e) Ts[(g + 32 + e) * LDP + r] = e1[e];
    __syncthreads();

    int d = tid >> 2;
    ushort_t* dst = Vt + ((size_t)bh * HDIM + d) * SEQ + s0;
    *(uint4*)(dst + g)      = *(const uint4*)(&Ts[d * LDP + g]);
    *(uint4*)(dst + g + 32) = *(const uint4*)(&Ts[d * LDP + g + 32]);
}

// ---------------- Flash attention v8: k-split halves, additive partials ----------------
// 8 waves/block. Waves 0-3 = strips 4p+0..3 over k-tiles [0,p]; waves 4-7 = same strips
// over k-tiles [p+1, 2p+1]. No running max (exp only) -> o,l are pure sums over k, so the
// two halves' partials just ADD (combined via dead staging LDS at epilogue). Block length
// = p+1 rounds (max 16): uniform-ish, longest-first dispatch -> no drain phase. Per-wave
// round: XOR-swizzled K/V dbuf, kappa-ordered PV, branched diagonal mask, ones-MFMA l.
// NOTE: VGPR ~128 caps at 4 waves/SIMD (pool 512/SIMD) -> 16 waves/CU = 2 blocks; LDS
// shrink cannot raise occupancy (checked R11).
__global__ __launch_bounds__(512, 4)
void flash_attn(const ushort_t* __restrict__ Q, const ushort_t* __restrict__ K,
                const ushort_t* __restrict__ Vt, ushort_t* __restrict__ O)
{
    const int xcd = blockIdx.x & 7, c = blockIdx.x >> 3;
    const int p  = 15 - (c >> 3);               // p=15 (longest) dispatched first
    const int bh = xcd * 8 + (c & 7);           // 8 bh per XCD -> K/V 4MB = L2-fit
    const int h = bh & 15, b = bh >> 4;
    const int t = threadIdx.x, w = t >> 6, lane = t & 63;
    const int wl = w & 3, hf = w >> 2;          // strip-lane, k-half
    const int l31 = lane & 31, hi = lane >> 5;
    const int s = 4 * p + wl;                   // this wave's strip (rows s*32..+31)
    const int sdiag = s >> 1;                   // strip's diagonal k-tile
    const int odd = s & 1;
    const int R = p + 1;                        // rounds per block
    const int jt0 = hf ? (p + 1) : 0;           // wave's first k-tile
    const size_t qkbase = (size_t)b * SEQ * EMBED + (size_t)h * HDIM;
    const size_t vtbase = (size_t)bh * HDIM * SEQ;

    // one 64KB arena: staging (8 x 8KB tiles) during loop, combine scratch at epilogue
    __shared__ __attribute__((aligned(16))) ushort_t smem[32768];
    // K tile (hf,d): smem + (hf*2+d)*4096 ; V tile: smem + 16384 + (hf*2+d)*4096

    // Q fragments (B-operand): lane holds Q[s*32+l31][ks*16 + hi*8 + 0..7]
    bf16x8 qb[4];
    {
        const ushort_t* qrow = Q + qkbase + (size_t)(s * 32 + l31) * EMBED + hi * 8;
        #pragma unroll
        for (int ks = 0; ks < 4; ++ks) qb[ks] = *(const bf16x8*)(qrow + ks * 16);
    }

    union { uint32_t u[4]; bf16x8 v; } onesu;
    onesu.u[0] = onesu.u[1] = onesu.u[2] = onesu.u[3] = 0x3F803F80u;
    const bf16x8 ones = onesu.v;

    // staging: within its half, wave wl covers rows wl*16..+15 (2 issues of 8 rows).
    // physical[row][cc] = global[row][cc ^ (row&7)]  (involution; read applies same XOR)
    const int rr = lane >> 3, cc = lane & 7;
    const ushort_t* Kg = K  + qkbase + (size_t)(jt0 * 64 + wl * 16 + rr) * EMBED + ((cc ^ rr) * 8);
    const ushort_t* Vg = Vt + vtbase + (size_t)(wl * 16 + rr) * SEQ + jt0 * 64 + ((cc ^ rr) * 8);

    f32x16 o0 = {}, o1 = {}, lac = {};
    const int swz = l31 & 7;

    // prologue: stage this half's tile jt0 into dbuf 0
    {
        ushort_t* kd = smem + (hf * 2 + 0) * 4096 + wl * 1024;
        ushort_t* vd = smem + 16384 + (hf * 2 + 0) * 4096 + wl * 1024;
        gl_lds16(Kg,             kd);
        gl_lds16(Kg + 8 * EMBED, kd + 512);
        gl_lds16(Vg,             vd);
        gl_lds16(Vg + 8 * SEQ,   vd + 512);
    }

    for (int r = 0; r < R; ++r) {
        const int cur = r & 1;
        __syncthreads();   // buf[cur] staged (vmcnt drained pre-barrier); prev reads done

        if (r + 1 < R) {   // stage next tile into the other dbuf; overlaps compute below
            const ushort_t* kg = Kg + (size_t)(r + 1) * 64 * EMBED;
            const ushort_t* vg = Vg + (r + 1) * 64;
            ushort_t* kd = smem + (hf * 2 + (cur ^ 1)) * 4096 + wl * 1024;
            ushort_t* vd = smem + 16384 + (hf * 2 + (cur ^ 1)) * 4096 + wl * 1024;
            gl_lds16(kg,             kd);
            gl_lds16(kg + 8 * EMBED, kd + 512);
            gl_lds16(vg,             vd);
            gl_lds16(vg + 8 * SEQ,   vd + 512);
        }

        const int jt = jt0 + r;
        if (jt <= sdiag) {                       // wave-uniform activity
            const ushort_t* Kst = smem + (hf * 2 + cur) * 4096;
            const ushort_t* Vst = smem + 16384 + (hf * 2 + cur) * 4096;
            const bool dg = (jt == sdiag);
            const bool skip1 = dg && !odd;       // even strip diagonal: st1 fully masked

            // S^T = mfma(K, Q): D[key][q], key = crow(r,hi) = (r&3)+8*(r>>2)+4*hi, q = l31
            f32x16 st0 = {}, st1 = {};
            #pragma unroll
            for (int ks = 0; ks < 4; ++ks) {
                bf16x8 k0 = *(const bf16x8*)(Kst + l31 * 64 + (((ks * 2 + hi) ^ swz) * 8));
                st0 = MFMA32(k0, qb[ks], st0, 0, 0, 0);
            }
            if (!skip1) {
                #pragma unroll
                for (int ks = 0; ks < 4; ++ks) {
                    bf16x8 k1 = *(const bf16x8*)(Kst + (32 + l31) * 64 + (((ks * 2 + hi) ^ swz) * 8));
                    st1 = MFMA32(k1, qb[ks], st1, 0, 0, 0);
                }
            }

            // exp + (diagonal-only) causal mask; P stays in native crow order
            bf16x8 pa0 = {}, pa1 = {}, pa2 = {}, pa3 = {};
            {
                float p0[16];
                #pragma unroll
                for (int r2 = 0; r2 < 16; ++r2) p0[r2] = exp2f_fast(st0[r2]);
                if (dg && !odd) {
                    #pragma unroll
                    for (int r2 = 0; r2 < 16; ++r2) {
                        int key = (r2 & 3) + 8 * (r2 >> 2) + 4 * hi;
                        if (key > l31) p0[r2] = 0.f;
                    }
                }
                #pragma unroll
                for (int e = 0; e < 8; ++e) { pa0[e] = (__bf16)p0[e]; pa1[e] = (__bf16)p0[8 + e]; }
                if (!skip1) {
                    float p1[16];
                    #pragma unroll
                    for (int r2 = 0; r2 < 16; ++r2) p1[r2] = exp2f_fast(st1[r2]);
                    if (dg && odd) {
                        #pragma unroll
                        for (int r2 = 0; r2 < 16; ++r2) {
                            int key = (r2 & 3) + 8 * (r2 >> 2) + 4 * hi;
                            if (key > l31) p1[r2] = 0.f;
                        }
                    }
                    #pragma unroll
                    for (int e = 0; e < 8; ++e) { pa2[e] = (__bf16)p1[e]; pa3[e] = (__bf16)p1[8 + e]; }
                }
            }

            // O += P V ; l += P 1  (kappa-ordered k-slots; A elem e <-> key slot*16+crow(e,hi))
            #pragma unroll
            for (int ksl = 0; ksl < 4; ++ksl) {
                if (!(ksl >= 2 && skip1)) {
                    bf16x8 pf = (ksl == 0) ? pa0 : (ksl == 1) ? pa1 : (ksl == 2) ? pa2 : pa3;
                    const int c0 = (((ksl * 2)     ^ swz) * 8) + hi * 4;
                    const int c1 = (((ksl * 2 + 1) ^ swz) * 8) + hi * 4;
                    union { bf16x4 hh[2]; bf16x8 v; } u0, u1;
                    u0.hh[0] = *(const bf16x4*)(Vst + l31 * 64 + c0);
                    u0.hh[1] = *(const bf16x4*)(Vst + l31 * 64 + c1);
                    u1.hh[0] = *(const bf16x4*)(Vst + (32 + l31) * 64 + c0);
                    u1.hh[1] = *(const bf16x4*)(Vst + (32 + l31) * 64 + c1);
                    o0  = MFMA32(pf, u0.v, o0, 0, 0, 0);
                    o1  = MFMA32(pf, u1.v, o1, 0, 0, 0);
                    lac = MFMA32(pf, ones, lac, 0, 0, 0);
                }
            }
        }
    }

    // ---- combine halves via (now-dead) staging LDS; only lower waves write O ----
    __syncthreads();                             // all staging/compute reads done
    float* Cs = (float*)smem;                    // [4][64][49] floats = 50,176 B
    if (hf) {
        float* dst = Cs + (wl * 64 + lane) * 49;
        #pragma unroll
        for (int r2 = 0; r2 < 16; ++r2) {
            dst[r2]      = o0[r2];
            dst[16 + r2] = o1[r2];
            dst[32 + r2] = lac[r2];
        }
    }
    __syncthreads();
    if (!hf) {
        const float* src = Cs + (wl * 64 + lane) * 49;
        #pragma unroll
        for (int r2 = 0; r2 < 16; ++r2) {
            float t0 = o0[r2]  + src[r2];
            float t1 = o1[r2]  + src[16 + r2];
            float lt = lac[r2] + src[32 + r2];
            float inv = 1.0f / lt;
            int q = (r2 & 3) + 8 * (r2 >> 2) + 4 * hi;
            size_t ob = qkbase + (size_t)(s * 32 + q) * EMBED;
            O[ob + l31]      = f2bf(t0 * inv);
            O[ob + 32 + l31] = f2bf(t1 * inv);
        }
    }
}

extern "C" void kernel_launch(void* const* d_in, const int* in_sizes, int n_in,
                              void* d_out, int out_size, void* d_ws, size_t ws_size,
                              hipStream_t stream)
{
    (void)in_sizes; (void)n_in; (void)out_size; (void)ws_size;
    const float* x  = (const float*)d_in[0];
    const float* Wq = (const float*)d_in[1];
    const float* bq = (const float*)d_in[2];
    const float* Wk = (const float*)d_in[3];
    const float* bk = (const float*)d_in[4];
    const float* Wv = (const float*)d_in[5];
    const float* bv = (const float*)d_in[6];
    const float* Wo = (const float*)d_in[7];
    const float* bo = (const float*)d_in[8];
    float* out = (float*)d_out;

    const int M = BATCH * SEQ;              // 8192
    size_t tsz = (size_t)M * EMBED;         // 8.4M elems (16.8 MB bf16)
    size_t wsz = (size_t)EMBED * EMBED;
    ushort_t* xb  = (ushort_t*)d_ws;
    ushort_t* Qb  = xb + tsz;
    ushort_t* Kb  = Qb + tsz;               // contiguous after Qb (merged GEMM relies on this)
    ushort_t* Vb  = Kb + tsz;
    ushort_t* Vt  = Vb + tsz;
    ushort_t* Wt0 = Vt + tsz;               // Wt0..Wt2 contiguous = concat QKV weights
    ushort_t* Wt3 = Wt0 + 3 * wsz;
    ushort_t* Ob  = xb;                     // alias: xb dead after QKV GEMM

    prep<<<5120, 256, 0, stream>>>(x, xb, Wq, Wk, Wv, Wo, Wt0);

    gemm_qkv<<<dim3(24, 32), 512, 0, stream>>>(xb, Wt0, bq, bk, bv, Qb, tsz);

    transpose_v<<<BATCH * HEADS * (SEQ / 64), 256, 0, stream>>>(Vb, Vt);
    flash_attn<<<1024, 512, 0, stream>>>(Qb, Kb, Vt, Ob);

    gemm_o<<<dim3(8, 64), 512, 0, stream>>>(Ob, Wt3, bo, out);
}

// Round 12
// 268.883 us; speedup vs baseline: 1.0096x; 1.0096x over previous
//
#include <hip/hip_runtime.h>
#include <stdint.h>

#define EMBED 1024
#define SEQ   2048
#define BATCH 4
#define HEADS 16
#define HDIM  64
#define LDP   72   // transpose_v LDS stride

typedef unsigned short ushort_t;
typedef __bf16 bf16x8 __attribute__((ext_vector_type(8)));
typedef __bf16 bf16x4 __attribute__((ext_vector_type(4)));
typedef float  f32x4  __attribute__((ext_vector_type(4)));
typedef float  f32x16 __attribute__((ext_vector_type(16)));

#define MFMA16 __builtin_amdgcn_mfma_f32_16x16x32_bf16
#define MFMA32 __builtin_amdgcn_mfma_f32_32x32x16_bf16

typedef __attribute__((address_space(3))) uint32_t lds_u32_t;
typedef __attribute__((address_space(1))) const uint32_t glb_u32_t;

// async global->LDS, 16 B/lane; LDS dest = wave-uniform base + lane*16 (m97/m104)
__device__ __forceinline__ void gl_lds16(const ushort_t* g, ushort_t* l) {
    __builtin_amdgcn_global_load_lds((glb_u32_t*)g, (lds_u32_t*)l, 16, 0, 0);
}

__device__ __forceinline__ ushort_t f2bf(float f) {
    union { float f; uint32_t u; } c; c.f = f;
    uint32_t u = c.u;
    return (ushort_t)((u + 0x7FFFu + ((u >> 16) & 1u)) >> 16);
}

// v_exp_f32 computes 2^x; log2(e) is folded into the Q scale in gemm_qkv
__device__ __forceinline__ float exp2f_fast(float x) {
    float r; asm("v_exp_f32 %0, %1" : "=v"(r) : "v"(x)); return r;
}

// ------- prep: cast x (blocks 0..4095) + cast/transpose 4 W (blocks 4096..5119) -------
__global__ __launch_bounds__(256)
void prep(const float* __restrict__ X, ushort_t* __restrict__ Xb,
          const float* __restrict__ W0, const float* __restrict__ W1,
          const float* __restrict__ W2, const float* __restrict__ W3,
          ushort_t* __restrict__ WtAll)
{
    __shared__ ushort_t Ts[64 * 80];
    const int t = threadIdx.x;
    if (blockIdx.x < 4096) {
        size_t i = ((size_t)blockIdx.x * 256 + t) * 8;
        ushort_t tmp[8];
        #pragma unroll
        for (int e = 0; e < 8; ++e) tmp[e] = f2bf(X[i + e]);
        *(uint4*)(Xb + i) = *(const uint4*)tmp;
        return;
    }
    const int rb = blockIdx.x - 4096;            // 0..1023
    const int z = rb >> 8, rem = rb & 255;
    const float* W = (z == 0) ? W0 : (z == 1) ? W1 : (z == 2) ? W2 : W3;
    ushort_t* Wt = WtAll + (size_t)z * EMBED * EMBED;
    const int k0 = (rem & 15) * 64, n0 = (rem >> 4) * 64;
    const int r = t >> 2, cs = (t & 3) * 16;
    const float* src = W + (size_t)(k0 + r) * EMBED + n0 + cs;
    #pragma unroll
    for (int e = 0; e < 16; ++e) Ts[(cs + e) * 80 + r] = f2bf(src[e]);
    __syncthreads();
    const int n = t >> 2, ks = (t & 3) * 16;
    ushort_t* dst = Wt + (size_t)(n0 + n) * EMBED + k0 + ks;
    *(uint4*)(dst)     = *(const uint4*)(&Ts[n * 80 + ks]);
    *(uint4*)(dst + 8) = *(const uint4*)(&Ts[n * 80 + ks + 8]);
}

// ---------------- merged QKV GEMM: [8192,3072] = xb @ WtQKV^T + bias ----------------
// m97 structure (verified R4/R9/R10, 71.5us, VGPR 80 -> 6 blocks/CU): 128x128 tile,
// BK=32, global_load_lds width-16 staging, 2-barrier K-loop. 4 waves 2x2, each 64x64.
// R12: T1 XCD-chunked swizzle — 1D grid 1536; XCD x owns bm in [x*8,x*8+8) x all 24 bn.
// With 6 blocks/CU the whole 192-block chunk is co-resident per XCD: A panels (2MB)
// become L2-resident single-fetch, B tiles get 8-way co-resident reuse.
// (R11's 256x128/8-wave tile regressed 71.5->77.2 — tile choice is structure-dependent.)
__global__ __launch_bounds__(256)
void gemm_qkv(const ushort_t* __restrict__ A, const ushort_t* __restrict__ Bt,
              const float* __restrict__ bq, const float* __restrict__ bk,
              const float* __restrict__ bv, ushort_t* __restrict__ Cq, size_t tsz)
{
    __shared__ ushort_t As[128 * 32];   // [m][k], unpadded (required by global_load_lds)
    __shared__ ushort_t Bs[128 * 32];   // [n][k]
    const int t = threadIdx.x;
    const int wave = t >> 6, lane = t & 63;
    const int l15 = lane & 15, quad = lane >> 4;
    // XCD-chunked decode: 1536 = 8 xcd x 8 bm_local x 24 bn (bijective)
    const int lid = blockIdx.x;
    const int xcd = lid & 7, c = lid >> 3;
    const int bm = xcd * 8 + (c & 7), bn = c >> 3;
    const int m0 = bm * 128, n0 = bn * 128;
    const int wm = (wave >> 1) * 64, wn = (wave & 1) * 64;
    f32x4 acc[4][4] = {};

    const int srow = wave * 32 + (lane >> 2), scol = (lane & 3) * 8;
    const ushort_t* Ag = A  + (size_t)(m0 + srow) * EMBED + scol;
    const ushort_t* Bg = Bt + (size_t)(n0 + srow) * EMBED + scol;
    ushort_t* AsW = As + wave * 1024;
    ushort_t* BsW = Bs + wave * 1024;

    for (int k0 = 0; k0 < EMBED; k0 += 32) {
        gl_lds16(Ag + k0,              AsW);
        gl_lds16(Ag + k0 + 16 * EMBED, AsW + 512);
        gl_lds16(Bg + k0,              BsW);
        gl_lds16(Bg + k0 + 16 * EMBED, BsW + 512);
        __syncthreads();

        bf16x8 af[4], bfr[4];
        #pragma unroll
        for (int mt = 0; mt < 4; ++mt)
            af[mt] = *(const bf16x8*)(&As[(wm + mt * 16 + l15) * 32 + quad * 8]);
        #pragma unroll
        for (int nt = 0; nt < 4; ++nt)
            bfr[nt] = *(const bf16x8*)(&Bs[(wn + nt * 16 + l15) * 32 + quad * 8]);
        #pragma unroll
        for (int mt = 0; mt < 4; ++mt)
            #pragma unroll
            for (int nt = 0; nt < 4; ++nt)
                acc[mt][nt] = MFMA16(af[mt], bfr[nt], acc[mt][nt], 0, 0, 0);
        __syncthreads();
    }

    const int mat = bn >> 3;
    const float* bias = (mat == 0) ? bq : (mat == 1) ? bk : bv;
    // Q scale = 1/sqrt(64) * log2(e): flash uses v_exp_f32 (2^x) directly
    const float scale = (mat == 0) ? 0.18033688011112042f : 1.0f;
    ushort_t* C = Cq + (size_t)mat * tsz;
    const int nc0 = (bn & 7) * 128;
    #pragma unroll
    for (int nt = 0; nt < 4; ++nt) {
        int col = nc0 + wn + nt * 16 + l15;
        float bb = bias[col];
        #pragma unroll
        for (int mt = 0; mt < 4; ++mt)
            #pragma unroll
            for (int r = 0; r < 4; ++r) {
                int row = m0 + wm + mt * 16 + quad * 4 + r;
                C[(size_t)row * EMBED + col] = f2bf((acc[mt][nt][r] + bb) * scale);
            }
    }
}

// ---------------- O-projection GEMM: out[8192,1024] fp32 = Ob @ Wt3^T + bo ----------------
// 8-wave 512-thread variant (verified R10): 128x128 tile, waves 2x4 each 64x32.
__global__ __launch_bounds__(512)
void gemm_o(const ushort_t* __restrict__ A, const ushort_t* __restrict__ Bt,
            const float* __restrict__ bias, float* __restrict__ C)
{
    __shared__ ushort_t As[128 * 32];
    __shared__ ushort_t Bs[128 * 32];
    const int t = threadIdx.x;
    const int wave = t >> 6, lane = t & 63;
    const int l15 = lane & 15, quad = lane >> 4;
    const int m0 = blockIdx.y * 128, n0 = blockIdx.x * 128;
    const int wmi = wave >> 2, wni = wave & 3;   // 2x4 wave grid: 64 rows x 32 cols each
    f32x4 acc[4][2] = {};

    const int srow = t >> 2, scol = (t & 3) * 8; // 512 threads cover 128x32 in one issue
    const ushort_t* Ag = A  + (size_t)(m0 + srow) * EMBED + scol;
    const ushort_t* Bg = Bt + (size_t)(n0 + srow) * EMBED + scol;
    ushort_t* AsW = As + wave * 512;             // 16 rows x 32 cols per wave
    ushort_t* BsW = Bs + wave * 512;

    for (int k0 = 0; k0 < EMBED; k0 += 32) {
        gl_lds16(Ag + k0, AsW);
        gl_lds16(Bg + k0, BsW);
        __syncthreads();

        bf16x8 af[4], bfr[2];
        #pragma unroll
        for (int mt = 0; mt < 4; ++mt)
            af[mt] = *(const bf16x8*)(&As[(wmi * 64 + mt * 16 + l15) * 32 + quad * 8]);
        #pragma unroll
        for (int nt = 0; nt < 2; ++nt)
            bfr[nt] = *(const bf16x8*)(&Bs[(wni * 32 + nt * 16 + l15) * 32 + quad * 8]);
        #pragma unroll
        for (int mt = 0; mt < 4; ++mt)
            #pragma unroll
            for (int nt = 0; nt < 2; ++nt)
                acc[mt][nt] = MFMA16(af[mt], bfr[nt], acc[mt][nt], 0, 0, 0);
        __syncthreads();
    }

    #pragma unroll
    for (int nt = 0; nt < 2; ++nt) {
        int col = n0 + wni * 32 + nt * 16 + l15;
        float bb = bias[col];
        #pragma unroll
        for (int mt = 0; mt < 4; ++mt)
            #pragma unroll
            for (int r = 0; r < 4; ++r) {
                int row = m0 + wmi * 64 + mt * 16 + quad * 4 + r;
                C[(size_t)row * EMBED + col] = acc[mt][nt][r] + bb;
            }
    }
}

// ---------------- V transpose: V[B,S,E] -> Vt[(b*H+h)*64+d][s] ----------------
__global__ __launch_bounds__(256)
void transpose_v(const ushort_t* __restrict__ V, ushort_t* __restrict__ Vt)
{
    int blk = blockIdx.x;
    int st = blk & 31, bh = blk >> 5;
    int h = bh & 15, b = bh >> 4;
    int s0 = st * 64;
    __shared__ ushort_t Ts[64 * LDP];
    int tid = threadIdx.x;
    int r = tid >> 2, g = (tid & 3) * 8;

    const ushort_t* src = V + ((size_t)(b * SEQ + s0 + r)) * EMBED + h * HDIM;
    uint4 v0 = *(const uint4*)(src + g);
    uint4 v1 = *(const uint4*)(src + g + 32);
    const ushort_t* e0 = (const ushort_t*)&v0;
    const ushort_t* e1 = (const ushort_t*)&v1;
    #pragma unroll
    for (int e = 0; e < 8; ++e) Ts[(g + e) * LDP + r] = e0[e];
    #pragma unroll
    for (int e = 0; e < 8; ++e) Ts[(g + 32 + e) * LDP + r] = e1[e];
    __syncthreads();

    int d = tid >> 2;
    ushort_t* dst = Vt + ((size_t)bh * HDIM + d) * SEQ + s0;
    *(uint4*)(dst + g)      = *(const uint4*)(&Ts[d * LDP + g]);
    *(uint4*)(dst + g + 32) = *(const uint4*)(&Ts[d * LDP + g + 32]);
}

// ---------------- Flash attention v8: k-split halves, additive partials ----------------
// 8 waves/block. Waves 0-3 = strips 4p+0..3 over k-tiles [0,p]; waves 4-7 = same strips
// over k-tiles [p+1, 2p+1]. No running max (exp only) -> o,l are pure sums over k, so the
// two halves' partials just ADD (combined via dead staging LDS at epilogue). Block length
// = p+1 rounds (max 16): uniform-ish, longest-first dispatch -> no drain phase. Per-wave
// round: XOR-swizzled K/V dbuf, kappa-ordered PV, branched diagonal mask, ones-MFMA l.
// R12: T5 setprio(1) around MFMA clusters — waves here have genuine role diversity
// (different strips/halves + 2 independent blocks/CU), the regime where m191 saw +4-7%.
__global__ __launch_bounds__(512, 4)
void flash_attn(const ushort_t* __restrict__ Q, const ushort_t* __restrict__ K,
                const ushort_t* __restrict__ Vt, ushort_t* __restrict__ O)
{
    const int xcd = blockIdx.x & 7, c = blockIdx.x >> 3;
    const int p  = 15 - (c >> 3);               // p=15 (longest) dispatched first
    const int bh = xcd * 8 + (c & 7);           // 8 bh per XCD -> K/V 4MB = L2-fit
    const int h = bh & 15, b = bh >> 4;
    const int t = threadIdx.x, w = t >> 6, lane = t & 63;
    const int wl = w & 3, hf = w >> 2;          // strip-lane, k-half
    const int l31 = lane & 31, hi = lane >> 5;
    const int s = 4 * p + wl;                   // this wave's strip (rows s*32..+31)
    const int sdiag = s >> 1;                   // strip's diagonal k-tile
    const int odd = s & 1;
    const int R = p + 1;                        // rounds per block
    const int jt0 = hf ? (p + 1) : 0;           // wave's first k-tile
    const size_t qkbase = (size_t)b * SEQ * EMBED + (size_t)h * HDIM;
    const size_t vtbase = (size_t)bh * HDIM * SEQ;

    // one 64KB arena: staging (8 x 8KB tiles) during loop, combine scratch at epilogue
    __shared__ __attribute__((aligned(16))) ushort_t smem[32768];
    // K tile (hf,d): smem + (hf*2+d)*4096 ; V tile: smem + 16384 + (hf*2+d)*4096

    // Q fragments (B-operand): lane holds Q[s*32+l31][ks*16 + hi*8 + 0..7]
    bf16x8 qb[4];
    {
        const ushort_t* qrow = Q + qkbase + (size_t)(s * 32 + l31) * EMBED + hi * 8;
        #pragma unroll
        for (int ks = 0; ks < 4; ++ks) qb[ks] = *(const bf16x8*)(qrow + ks * 16);
    }

    union { uint32_t u[4]; bf16x8 v; } onesu;
    onesu.u[0] = onesu.u[1] = onesu.u[2] = onesu.u[3] = 0x3F803F80u;
    const bf16x8 ones = onesu.v;

    // staging: within its half, wave wl covers rows wl*16..+15 (2 issues of 8 rows).
    // physical[row][cc] = global[row][cc ^ (row&7)]  (involution; read applies same XOR)
    const int rr = lane >> 3, cc = lane & 7;
    const ushort_t* Kg = K  + qkbase + (size_t)(jt0 * 64 + wl * 16 + rr) * EMBED + ((cc ^ rr) * 8);
    const ushort_t* Vg = Vt + vtbase + (size_t)(wl * 16 + rr) * SEQ + jt0 * 64 + ((cc ^ rr) * 8);

    f32x16 o0 = {}, o1 = {}, lac = {};
    const int swz = l31 & 7;

    // prologue: stage this half's tile jt0 into dbuf 0
    {
        ushort_t* kd = smem + (hf * 2 + 0) * 4096 + wl * 1024;
        ushort_t* vd = smem + 16384 + (hf * 2 + 0) * 4096 + wl * 1024;
        gl_lds16(Kg,             kd);
        gl_lds16(Kg + 8 * EMBED, kd + 512);
        gl_lds16(Vg,             vd);
        gl_lds16(Vg + 8 * SEQ,   vd + 512);
    }

    for (int r = 0; r < R; ++r) {
        const int cur = r & 1;
        __syncthreads();   // buf[cur] staged (vmcnt drained pre-barrier); prev reads done

        if (r + 1 < R) {   // stage next tile into the other dbuf; overlaps compute below
            const ushort_t* kg = Kg + (size_t)(r + 1) * 64 * EMBED;
            const ushort_t* vg = Vg + (r + 1) * 64;
            ushort_t* kd = smem + (hf * 2 + (cur ^ 1)) * 4096 + wl * 1024;
            ushort_t* vd = smem + 16384 + (hf * 2 + (cur ^ 1)) * 4096 + wl * 1024;
            gl_lds16(kg,             kd);
            gl_lds16(kg + 8 * EMBED, kd + 512);
            gl_lds16(vg,             vd);
            gl_lds16(vg + 8 * SEQ,   vd + 512);
        }

        const int jt = jt0 + r;
        if (jt <= sdiag) {                       // wave-uniform activity
            const ushort_t* Kst = smem + (hf * 2 + cur) * 4096;
            const ushort_t* Vst = smem + 16384 + (hf * 2 + cur) * 4096;
            const bool dg = (jt == sdiag);
            const bool skip1 = dg && !odd;       // even strip diagonal: st1 fully masked

            // S^T = mfma(K, Q): D[key][q], key = crow(r,hi) = (r&3)+8*(r>>2)+4*hi, q = l31
            f32x16 st0 = {}, st1 = {};
            __builtin_amdgcn_s_setprio(1);
            #pragma unroll
            for (int ks = 0; ks < 4; ++ks) {
                bf16x8 k0 = *(const bf16x8*)(Kst + l31 * 64 + (((ks * 2 + hi) ^ swz) * 8));
                st0 = MFMA32(k0, qb[ks], st0, 0, 0, 0);
            }
            if (!skip1) {
                #pragma unroll
                for (int ks = 0; ks < 4; ++ks) {
                    bf16x8 k1 = *(const bf16x8*)(Kst + (32 + l31) * 64 + (((ks * 2 + hi) ^ swz) * 8));
                    st1 = MFMA32(k1, qb[ks], st1, 0, 0, 0);
                }
            }
            __builtin_amdgcn_s_setprio(0);

            // exp + (diagonal-only) causal mask; P stays in native crow order
            bf16x8 pa0 = {}, pa1 = {}, pa2 = {}, pa3 = {};
            {
                float p0[16];
                #pragma unroll
                for (int r2 = 0; r2 < 16; ++r2) p0[r2] = exp2f_fast(st0[r2]);
                if (dg && !odd) {
                    #pragma unroll
                    for (int r2 = 0; r2 < 16; ++r2) {
                        int key = (r2 & 3) + 8 * (r2 >> 2) + 4 * hi;
                        if (key > l31) p0[r2] = 0.f;
                    }
                }
                #pragma unroll
                for (int e = 0; e < 8; ++e) { pa0[e] = (__bf16)p0[e]; pa1[e] = (__bf16)p0[8 + e]; }
                if (!skip1) {
                    float p1[16];
                    #pragma unroll
                    for (int r2 = 0; r2 < 16; ++r2) p1[r2] = exp2f_fast(st1[r2]);
                    if (dg && odd) {
                        #pragma unroll
                        for (int r2 = 0; r2 < 16; ++r2) {
                            int key = (r2 & 3) + 8 * (r2 >> 2) + 4 * hi;
                            if (key > l31) p1[r2] = 0.f;
                        }
                    }
                    #pragma unroll
                    for (int e = 0; e < 8; ++e) { pa2[e] = (__bf16)p1[e]; pa3[e] = (__bf16)p1[8 + e]; }
                }
            }

            // O += P V ; l += P 1  (kappa-ordered k-slots; A elem e <-> key slot*16+crow(e,hi))
            __builtin_amdgcn_s_setprio(1);
            #pragma unroll
            for (int ksl = 0; ksl < 4; ++ksl) {
                if (!(ksl >= 2 && skip1)) {
                    bf16x8 pf = (ksl == 0) ? pa0 : (ksl == 1) ? pa1 : (ksl == 2) ? pa2 : pa3;
                    const int c0 = (((ksl * 2)     ^ swz) * 8) + hi * 4;
                    const int c1 = (((ksl * 2 + 1) ^ swz) * 8) + hi * 4;
                    union { bf16x4 hh[2]; bf16x8 v; } u0, u1;
                    u0.hh[0] = *(const bf16x4*)(Vst + l31 * 64 + c0);
                    u0.hh[1] = *(const bf16x4*)(Vst + l31 * 64 + c1);
                    u1.hh[0] = *(const bf16x4*)(Vst + (32 + l31) * 64 + c0);
                    u1.hh[1] = *(const bf16x4*)(Vst + (32 + l31) * 64 + c1);
                    o0  = MFMA32(pf, u0.v, o0, 0, 0, 0);
                    o1  = MFMA32(pf, u1.v, o1, 0, 0, 0);
                    lac = MFMA32(pf, ones, lac, 0, 0, 0);
                }
            }
            __builtin_amdgcn_s_setprio(0);
        }
    }

    // ---- combine halves via (now-dead) staging LDS; only lower waves write O ----
    __syncthreads();                             // all staging/compute reads done
    float* Cs = (float*)smem;                    // [4][64][49] floats = 50,176 B
    if (hf) {
        float* dst = Cs + (wl * 64 + lane) * 49;
        #pragma unroll
        for (int r2 = 0; r2 < 16; ++r2) {
            dst[r2]      = o0[r2];
            dst[16 + r2] = o1[r2];
            dst[32 + r2] = lac[r2];
        }
    }
    __syncthreads();
    if (!hf) {
        const float* src = Cs + (wl * 64 + lane) * 49;
        #pragma unroll
        for (int r2 = 0; r2 < 16; ++r2) {
            float t0 = o0[r2]  + src[r2];
            float t1 = o1[r2]  + src[16 + r2];
            float lt = lac[r2] + src[32 + r2];
            float inv = 1.0f / lt;
            int q = (r2 & 3) + 8 * (r2 >> 2) + 4 * hi;
            size_t ob = qkbase + (size_t)(s * 32 + q) * EMBED;
            O[ob + l31]      = f2bf(t0 * inv);
            O[ob + 32 + l31] = f2bf(t1 * inv);
        }
    }
}

extern "C" void kernel_launch(void* const* d_in, const int* in_sizes, int n_in,
                              void* d_out, int out_size, void* d_ws, size_t ws_size,
                              hipStream_t stream)
{
    (void)in_sizes; (void)n_in; (void)out_size; (void)ws_size;
    const float* x  = (const float*)d_in[0];
    const float* Wq = (const float*)d_in[1];
    const float* bq = (const float*)d_in[2];
    const float* Wk = (const float*)d_in[3];
    const float* bk = (const float*)d_in[4];
    const float* Wv = (const float*)d_in[5];
    const float* bv = (const float*)d_in[6];
    const float* Wo = (const float*)d_in[7];
    const float* bo = (const float*)d_in[8];
    float* out = (float*)d_out;

    const int M = BATCH * SEQ;              // 8192
    size_t tsz = (size_t)M * EMBED;         // 8.4M elems (16.8 MB bf16)
    size_t wsz = (size_t)EMBED * EMBED;
    ushort_t* xb  = (ushort_t*)d_ws;
    ushort_t* Qb  = xb + tsz;
    ushort_t* Kb  = Qb + tsz;               // contiguous after Qb (merged GEMM relies on this)
    ushort_t* Vb  = Kb + tsz;
    ushort_t* Vt  = Vb + tsz;
    ushort_t* Wt0 = Vt + tsz;               // Wt0..Wt2 contiguous = concat QKV weights
    ushort_t* Wt3 = Wt0 + 3 * wsz;
    ushort_t* Ob  = xb;                     // alias: xb dead after QKV GEMM

    prep<<<5120, 256, 0, stream>>>(x, xb, Wq, Wk, Wv, Wo, Wt0);

    gemm_qkv<<<1536, 256, 0, stream>>>(xb, Wt0, bq, bk, bv, Qb, tsz);

    transpose_v<<<BATCH * HEADS * (SEQ / 64), 256, 0, stream>>>(Vb, Vt);
    flash_attn<<<1024, 512, 0, stream>>>(Qb, Kb, Vt, Ob);

    gemm_o<<<dim3(8, 64), 512, 0, stream>>>(Ob, Wt3, bo, out);
}

// Round 13
// 255.744 us; speedup vs baseline: 1.0614x; 1.0514x over previous
//
#include <hip/hip_runtime.h>
#include <stdint.h>

#define EMBED 1024
#define SEQ   2048
#define BATCH 4
#define HEADS 16
#define HDIM  64
#define LDP   72   // transpose_v LDS stride

typedef unsigned short ushort_t;
typedef __bf16 bf16x8 __attribute__((ext_vector_type(8)));
typedef __bf16 bf16x4 __attribute__((ext_vector_type(4)));
typedef float  f32x4  __attribute__((ext_vector_type(4)));
typedef float  f32x16 __attribute__((ext_vector_type(16)));

#define MFMA16 __builtin_amdgcn_mfma_f32_16x16x32_bf16
#define MFMA32 __builtin_amdgcn_mfma_f32_32x32x16_bf16

typedef __attribute__((address_space(3))) uint32_t lds_u32_t;
typedef __attribute__((address_space(1))) const uint32_t glb_u32_t;

// async global->LDS, 16 B/lane; LDS dest = wave-uniform base + lane*16 (m97/m104)
__device__ __forceinline__ void gl_lds16(const ushort_t* g, ushort_t* l) {
    __builtin_amdgcn_global_load_lds((glb_u32_t*)g, (lds_u32_t*)l, 16, 0, 0);
}

__device__ __forceinline__ ushort_t f2bf(float f) {
    union { float f; uint32_t u; } c; c.f = f;
    uint32_t u = c.u;
    return (ushort_t)((u + 0x7FFFu + ((u >> 16) & 1u)) >> 16);
}

// v_exp_f32 computes 2^x; log2(e) is folded into the Q scale in gemm_qkv
__device__ __forceinline__ float exp2f_fast(float x) {
    float r; asm("v_exp_f32 %0, %1" : "=v"(r) : "v"(x)); return r;
}

// ------- prep: cast x (blocks 0..4095) + cast/transpose 4 W (blocks 4096..5119) -------
__global__ __launch_bounds__(256)
void prep(const float* __restrict__ X, ushort_t* __restrict__ Xb,
          const float* __restrict__ W0, const float* __restrict__ W1,
          const float* __restrict__ W2, const float* __restrict__ W3,
          ushort_t* __restrict__ WtAll)
{
    __shared__ ushort_t Ts[64 * 80];
    const int t = threadIdx.x;
    if (blockIdx.x < 4096) {
        size_t i = ((size_t)blockIdx.x * 256 + t) * 8;
        ushort_t tmp[8];
        #pragma unroll
        for (int e = 0; e < 8; ++e) tmp[e] = f2bf(X[i + e]);
        *(uint4*)(Xb + i) = *(const uint4*)tmp;
        return;
    }
    const int rb = blockIdx.x - 4096;            // 0..1023
    const int z = rb >> 8, rem = rb & 255;
    const float* W = (z == 0) ? W0 : (z == 1) ? W1 : (z == 2) ? W2 : W3;
    ushort_t* Wt = WtAll + (size_t)z * EMBED * EMBED;
    const int k0 = (rem & 15) * 64, n0 = (rem >> 4) * 64;
    const int r = t >> 2, cs = (t & 3) * 16;
    const float* src = W + (size_t)(k0 + r) * EMBED + n0 + cs;
    #pragma unroll
    for (int e = 0; e < 16; ++e) Ts[(cs + e) * 80 + r] = f2bf(src[e]);
    __syncthreads();
    const int n = t >> 2, ks = (t & 3) * 16;
    ushort_t* dst = Wt + (size_t)(n0 + n) * EMBED + k0 + ks;
    *(uint4*)(dst)     = *(const uint4*)(&Ts[n * 80 + ks]);
    *(uint4*)(dst + 8) = *(const uint4*)(&Ts[n * 80 + ks + 8]);
}

// ---------------- merged QKV GEMM: [8192,3072] = xb @ WtQKV^T + bias ----------------
// m97 structure (verified R4/R9/R10, 71.5us, VGPR 80 -> 6 blocks/CU): 128x128 tile,
// BK=32, global_load_lds width-16 staging, 2-barrier K-loop. 4 waves 2x2, each 64x64.
// R13: zero-cost XCD A-chunking — grid dim3(64,24), x=bm, y=bn. Linear id = y*64+x,
// round-robin XCD (confirmed by R12's FETCH drop) => XCD = bm%8: each XCD owns 8
// A-panels (2MB, L2-resident) x all 24 bn. Decode is pure special-reg reads, so VGPR
// stays 80 (R12's 1D remap cost +8 VGPR -> 5 waves/SIMD -> +8us; this form is free).
__global__ __launch_bounds__(256)
void gemm_qkv(const ushort_t* __restrict__ A, const ushort_t* __restrict__ Bt,
              const float* __restrict__ bq, const float* __restrict__ bk,
              const float* __restrict__ bv, ushort_t* __restrict__ Cq, size_t tsz)
{
    __shared__ ushort_t As[128 * 32];   // [m][k], unpadded (required by global_load_lds)
    __shared__ ushort_t Bs[128 * 32];   // [n][k]
    const int t = threadIdx.x;
    const int wave = t >> 6, lane = t & 63;
    const int l15 = lane & 15, quad = lane >> 4;
    const int m0 = blockIdx.x * 128, n0 = blockIdx.y * 128;   // x=bm, y=bn
    const int wm = (wave >> 1) * 64, wn = (wave & 1) * 64;
    f32x4 acc[4][4] = {};

    const int srow = wave * 32 + (lane >> 2), scol = (lane & 3) * 8;
    const ushort_t* Ag = A  + (size_t)(m0 + srow) * EMBED + scol;
    const ushort_t* Bg = Bt + (size_t)(n0 + srow) * EMBED + scol;
    ushort_t* AsW = As + wave * 1024;
    ushort_t* BsW = Bs + wave * 1024;

    for (int k0 = 0; k0 < EMBED; k0 += 32) {
        gl_lds16(Ag + k0,              AsW);
        gl_lds16(Ag + k0 + 16 * EMBED, AsW + 512);
        gl_lds16(Bg + k0,              BsW);
        gl_lds16(Bg + k0 + 16 * EMBED, BsW + 512);
        __syncthreads();

        bf16x8 af[4], bfr[4];
        #pragma unroll
        for (int mt = 0; mt < 4; ++mt)
            af[mt] = *(const bf16x8*)(&As[(wm + mt * 16 + l15) * 32 + quad * 8]);
        #pragma unroll
        for (int nt = 0; nt < 4; ++nt)
            bfr[nt] = *(const bf16x8*)(&Bs[(wn + nt * 16 + l15) * 32 + quad * 8]);
        #pragma unroll
        for (int mt = 0; mt < 4; ++mt)
            #pragma unroll
            for (int nt = 0; nt < 4; ++nt)
                acc[mt][nt] = MFMA16(af[mt], bfr[nt], acc[mt][nt], 0, 0, 0);
        __syncthreads();
    }

    const int mat = blockIdx.y >> 3;
    const float* bias = (mat == 0) ? bq : (mat == 1) ? bk : bv;
    // Q scale = 1/sqrt(64) * log2(e): flash uses v_exp_f32 (2^x) directly
    const float scale = (mat == 0) ? 0.18033688011112042f : 1.0f;
    ushort_t* C = Cq + (size_t)mat * tsz;
    const int nc0 = (blockIdx.y & 7) * 128;
    #pragma unroll
    for (int nt = 0; nt < 4; ++nt) {
        int col = nc0 + wn + nt * 16 + l15;
        float bb = bias[col];
        #pragma unroll
        for (int mt = 0; mt < 4; ++mt)
            #pragma unroll
            for (int r = 0; r < 4; ++r) {
                int row = m0 + wm + mt * 16 + quad * 4 + r;
                C[(size_t)row * EMBED + col] = f2bf((acc[mt][nt][r] + bb) * scale);
            }
    }
}

// ---------------- O-projection GEMM: out[8192,1024] fp32 = Ob @ Wt3^T + bo ----------------
// 8-wave 512-thread variant (verified R10): 128x128 tile, waves 2x4 each 64x32.
__global__ __launch_bounds__(512)
void gemm_o(const ushort_t* __restrict__ A, const ushort_t* __restrict__ Bt,
            const float* __restrict__ bias, float* __restrict__ C)
{
    __shared__ ushort_t As[128 * 32];
    __shared__ ushort_t Bs[128 * 32];
    const int t = threadIdx.x;
    const int wave = t >> 6, lane = t & 63;
    const int l15 = lane & 15, quad = lane >> 4;
    const int m0 = blockIdx.y * 128, n0 = blockIdx.x * 128;
    const int wmi = wave >> 2, wni = wave & 3;   // 2x4 wave grid: 64 rows x 32 cols each
    f32x4 acc[4][2] = {};

    const int srow = t >> 2, scol = (t & 3) * 8; // 512 threads cover 128x32 in one issue
    const ushort_t* Ag = A  + (size_t)(m0 + srow) * EMBED + scol;
    const ushort_t* Bg = Bt + (size_t)(n0 + srow) * EMBED + scol;
    ushort_t* AsW = As + wave * 512;             // 16 rows x 32 cols per wave
    ushort_t* BsW = Bs + wave * 512;

    for (int k0 = 0; k0 < EMBED; k0 += 32) {
        gl_lds16(Ag + k0, AsW);
        gl_lds16(Bg + k0, BsW);
        __syncthreads();

        bf16x8 af[4], bfr[2];
        #pragma unroll
        for (int mt = 0; mt < 4; ++mt)
            af[mt] = *(const bf16x8*)(&As[(wmi * 64 + mt * 16 + l15) * 32 + quad * 8]);
        #pragma unroll
        for (int nt = 0; nt < 2; ++nt)
            bfr[nt] = *(const bf16x8*)(&Bs[(wni * 32 + nt * 16 + l15) * 32 + quad * 8]);
        #pragma unroll
        for (int mt = 0; mt < 4; ++mt)
            #pragma unroll
            for (int nt = 0; nt < 2; ++nt)
                acc[mt][nt] = MFMA16(af[mt], bfr[nt], acc[mt][nt], 0, 0, 0);
        __syncthreads();
    }

    #pragma unroll
    for (int nt = 0; nt < 2; ++nt) {
        int col = n0 + wni * 32 + nt * 16 + l15;
        float bb = bias[col];
        #pragma unroll
        for (int mt = 0; mt < 4; ++mt)
            #pragma unroll
            for (int r = 0; r < 4; ++r) {
                int row = m0 + wmi * 64 + mt * 16 + quad * 4 + r;
                C[(size_t)row * EMBED + col] = acc[mt][nt][r] + bb;
            }
    }
}

// ---------------- V transpose: V[B,S,E] -> Vt[(b*H+h)*64+d][s] ----------------
__global__ __launch_bounds__(256)
void transpose_v(const ushort_t* __restrict__ V, ushort_t* __restrict__ Vt)
{
    int blk = blockIdx.x;
    int st = blk & 31, bh = blk >> 5;
    int h = bh & 15, b = bh >> 4;
    int s0 = st * 64;
    __shared__ ushort_t Ts[64 * LDP];
    int tid = threadIdx.x;
    int r = tid >> 2, g = (tid & 3) * 8;

    const ushort_t* src = V + ((size_t)(b * SEQ + s0 + r)) * EMBED + h * HDIM;
    uint4 v0 = *(const uint4*)(src + g);
    uint4 v1 = *(const uint4*)(src + g + 32);
    const ushort_t* e0 = (const ushort_t*)&v0;
    const ushort_t* e1 = (const ushort_t*)&v1;
    #pragma unroll
    for (int e = 0; e < 8; ++e) Ts[(g + e) * LDP + r] = e0[e];
    #pragma unroll
    for (int e = 0; e < 8; ++e) Ts[(g + 32 + e) * LDP + r] = e1[e];
    __syncthreads();

    int d = tid >> 2;
    ushort_t* dst = Vt + ((size_t)bh * HDIM + d) * SEQ + s0;
    *(uint4*)(dst + g)      = *(const uint4*)(&Ts[d * LDP + g]);
    *(uint4*)(dst + g + 32) = *(const uint4*)(&Ts[d * LDP + g + 32]);
}

// ---------------- Flash attention v8: k-split halves, additive partials ----------------
// 8 waves/block. Waves 0-3 = strips 4p+0..3 over k-tiles [0,p]; waves 4-7 = same strips
// over k-tiles [p+1, 2p+1]. No running max (exp only) -> o,l are pure sums over k, so the
// two halves' partials just ADD (combined via dead staging LDS at epilogue). Block length
// = p+1 rounds (max 16): uniform-ish, longest-first dispatch -> no drain phase. Per-wave
// round: XOR-swizzled K/V dbuf, kappa-ordered PV, branched diagonal mask, ones-MFMA l.
// T5 setprio(1) around MFMA clusters (kept from R12: ~-2us, wave role diversity regime).
__global__ __launch_bounds__(512, 4)
void flash_attn(const ushort_t* __restrict__ Q, const ushort_t* __restrict__ K,
                const ushort_t* __restrict__ Vt, ushort_t* __restrict__ O)
{
    const int xcd = blockIdx.x & 7, c = blockIdx.x >> 3;
    const int p  = 15 - (c >> 3);               // p=15 (longest) dispatched first
    const int bh = xcd * 8 + (c & 7);           // 8 bh per XCD -> K/V 4MB = L2-fit
    const int h = bh & 15, b = bh >> 4;
    const int t = threadIdx.x, w = t >> 6, lane = t & 63;
    const int wl = w & 3, hf = w >> 2;          // strip-lane, k-half
    const int l31 = lane & 31, hi = lane >> 5;
    const int s = 4 * p + wl;                   // this wave's strip (rows s*32..+31)
    const int sdiag = s >> 1;                   // strip's diagonal k-tile
    const int odd = s & 1;
    const int R = p + 1;                        // rounds per block
    const int jt0 = hf ? (p + 1) : 0;           // wave's first k-tile
    const size_t qkbase = (size_t)b * SEQ * EMBED + (size_t)h * HDIM;
    const size_t vtbase = (size_t)bh * HDIM * SEQ;

    // one 64KB arena: staging (8 x 8KB tiles) during loop, combine scratch at epilogue
    __shared__ __attribute__((aligned(16))) ushort_t smem[32768];
    // K tile (hf,d): smem + (hf*2+d)*4096 ; V tile: smem + 16384 + (hf*2+d)*4096

    // Q fragments (B-operand): lane holds Q[s*32+l31][ks*16 + hi*8 + 0..7]
    bf16x8 qb[4];
    {
        const ushort_t* qrow = Q + qkbase + (size_t)(s * 32 + l31) * EMBED + hi * 8;
        #pragma unroll
        for (int ks = 0; ks < 4; ++ks) qb[ks] = *(const bf16x8*)(qrow + ks * 16);
    }

    union { uint32_t u[4]; bf16x8 v; } onesu;
    onesu.u[0] = onesu.u[1] = onesu.u[2] = onesu.u[3] = 0x3F803F80u;
    const bf16x8 ones = onesu.v;

    // staging: within its half, wave wl covers rows wl*16..+15 (2 issues of 8 rows).
    // physical[row][cc] = global[row][cc ^ (row&7)]  (involution; read applies same XOR)
    const int rr = lane >> 3, cc = lane & 7;
    const ushort_t* Kg = K  + qkbase + (size_t)(jt0 * 64 + wl * 16 + rr) * EMBED + ((cc ^ rr) * 8);
    const ushort_t* Vg = Vt + vtbase + (size_t)(wl * 16 + rr) * SEQ + jt0 * 64 + ((cc ^ rr) * 8);

    f32x16 o0 = {}, o1 = {}, lac = {};
    const int swz = l31 & 7;

    // prologue: stage this half's tile jt0 into dbuf 0
    {
        ushort_t* kd = smem + (hf * 2 + 0) * 4096 + wl * 1024;
        ushort_t* vd = smem + 16384 + (hf * 2 + 0) * 4096 + wl * 1024;
        gl_lds16(Kg,             kd);
        gl_lds16(Kg + 8 * EMBED, kd + 512);
        gl_lds16(Vg,             vd);
        gl_lds16(Vg + 8 * SEQ,   vd + 512);
    }

    for (int r = 0; r < R; ++r) {
        const int cur = r & 1;
        __syncthreads();   // buf[cur] staged (vmcnt drained pre-barrier); prev reads done

        if (r + 1 < R) {   // stage next tile into the other dbuf; overlaps compute below
            const ushort_t* kg = Kg + (size_t)(r + 1) * 64 * EMBED;
            const ushort_t* vg = Vg + (r + 1) * 64;
            ushort_t* kd = smem + (hf * 2 + (cur ^ 1)) * 4096 + wl * 1024;
            ushort_t* vd = smem + 16384 + (hf * 2 + (cur ^ 1)) * 4096 + wl * 1024;
            gl_lds16(kg,             kd);
            gl_lds16(kg + 8 * EMBED, kd + 512);
            gl_lds16(vg,             vd);
            gl_lds16(vg + 8 * SEQ,   vd + 512);
        }

        const int jt = jt0 + r;
        if (jt <= sdiag) {                       // wave-uniform activity
            const ushort_t* Kst = smem + (hf * 2 + cur) * 4096;
            const ushort_t* Vst = smem + 16384 + (hf * 2 + cur) * 4096;
            const bool dg = (jt == sdiag);
            const bool skip1 = dg && !odd;       // even strip diagonal: st1 fully masked

            // S^T = mfma(K, Q): D[key][q], key = crow(r,hi) = (r&3)+8*(r>>2)+4*hi, q = l31
            f32x16 st0 = {}, st1 = {};
            __builtin_amdgcn_s_setprio(1);
            #pragma unroll
            for (int ks = 0; ks < 4; ++ks) {
                bf16x8 k0 = *(const bf16x8*)(Kst + l31 * 64 + (((ks * 2 + hi) ^ swz) * 8));
                st0 = MFMA32(k0, qb[ks], st0, 0, 0, 0);
            }
            if (!skip1) {
                #pragma unroll
                for (int ks = 0; ks < 4; ++ks) {
                    bf16x8 k1 = *(const bf16x8*)(Kst + (32 + l31) * 64 + (((ks * 2 + hi) ^ swz) * 8));
                    st1 = MFMA32(k1, qb[ks], st1, 0, 0, 0);
                }
            }
            __builtin_amdgcn_s_setprio(0);

            // exp + (diagonal-only) causal mask; P stays in native crow order
            bf16x8 pa0 = {}, pa1 = {}, pa2 = {}, pa3 = {};
            {
                float p0[16];
                #pragma unroll
                for (int r2 = 0; r2 < 16; ++r2) p0[r2] = exp2f_fast(st0[r2]);
                if (dg && !odd) {
                    #pragma unroll
                    for (int r2 = 0; r2 < 16; ++r2) {
                        int key = (r2 & 3) + 8 * (r2 >> 2) + 4 * hi;
                        if (key > l31) p0[r2] = 0.f;
                    }
                }
                #pragma unroll
                for (int e = 0; e < 8; ++e) { pa0[e] = (__bf16)p0[e]; pa1[e] = (__bf16)p0[8 + e]; }
                if (!skip1) {
                    float p1[16];
                    #pragma unroll
                    for (int r2 = 0; r2 < 16; ++r2) p1[r2] = exp2f_fast(st1[r2]);
                    if (dg && odd) {
                        #pragma unroll
                        for (int r2 = 0; r2 < 16; ++r2) {
                            int key = (r2 & 3) + 8 * (r2 >> 2) + 4 * hi;
                            if (key > l31) p1[r2] = 0.f;
                        }
                    }
                    #pragma unroll
                    for (int e = 0; e < 8; ++e) { pa2[e] = (__bf16)p1[e]; pa3[e] = (__bf16)p1[8 + e]; }
                }
            }

            // O += P V ; l += P 1  (kappa-ordered k-slots; A elem e <-> key slot*16+crow(e,hi))
            __builtin_amdgcn_s_setprio(1);
            #pragma unroll
            for (int ksl = 0; ksl < 4; ++ksl) {
                if (!(ksl >= 2 && skip1)) {
                    bf16x8 pf = (ksl == 0) ? pa0 : (ksl == 1) ? pa1 : (ksl == 2) ? pa2 : pa3;
                    const int c0 = (((ksl * 2)     ^ swz) * 8) + hi * 4;
                    const int c1 = (((ksl * 2 + 1) ^ swz) * 8) + hi * 4;
                    union { bf16x4 hh[2]; bf16x8 v; } u0, u1;
                    u0.hh[0] = *(const bf16x4*)(Vst + l31 * 64 + c0);
                    u0.hh[1] = *(const bf16x4*)(Vst + l31 * 64 + c1);
                    u1.hh[0] = *(const bf16x4*)(Vst + (32 + l31) * 64 + c0);
                    u1.hh[1] = *(const bf16x4*)(Vst + (32 + l31) * 64 + c1);
                    o0  = MFMA32(pf, u0.v, o0, 0, 0, 0);
                    o1  = MFMA32(pf, u1.v, o1, 0, 0, 0);
                    lac = MFMA32(pf, ones, lac, 0, 0, 0);
                }
            }
            __builtin_amdgcn_s_setprio(0);
        }
    }

    // ---- combine halves via (now-dead) staging LDS; only lower waves write O ----
    __syncthreads();                             // all staging/compute reads done
    float* Cs = (float*)smem;                    // [4][64][49] floats = 50,176 B
    if (hf) {
        float* dst = Cs + (wl * 64 + lane) * 49;
        #pragma unroll
        for (int r2 = 0; r2 < 16; ++r2) {
            dst[r2]      = o0[r2];
            dst[16 + r2] = o1[r2];
            dst[32 + r2] = lac[r2];
        }
    }
    __syncthreads();
    if (!hf) {
        const float* src = Cs + (wl * 64 + lane) * 49;
        #pragma unroll
        for (int r2 = 0; r2 < 16; ++r2) {
            float t0 = o0[r2]  + src[r2];
            float t1 = o1[r2]  + src[16 + r2];
            float lt = lac[r2] + src[32 + r2];
            float inv = 1.0f / lt;
            int q = (r2 & 3) + 8 * (r2 >> 2) + 4 * hi;
            size_t ob = qkbase + (size_t)(s * 32 + q) * EMBED;
            O[ob + l31]      = f2bf(t0 * inv);
            O[ob + 32 + l31] = f2bf(t1 * inv);
        }
    }
}

extern "C" void kernel_launch(void* const* d_in, const int* in_sizes, int n_in,
                              void* d_out, int out_size, void* d_ws, size_t ws_size,
                              hipStream_t stream)
{
    (void)in_sizes; (void)n_in; (void)out_size; (void)ws_size;
    const float* x  = (const float*)d_in[0];
    const float* Wq = (const float*)d_in[1];
    const float* bq = (const float*)d_in[2];
    const float* Wk = (const float*)d_in[3];
    const float* bk = (const float*)d_in[4];
    const float* Wv = (const float*)d_in[5];
    const float* bv = (const float*)d_in[6];
    const float* Wo = (const float*)d_in[7];
    const float* bo = (const float*)d_in[8];
    float* out = (float*)d_out;

    const int M = BATCH * SEQ;              // 8192
    size_t tsz = (size_t)M * EMBED;         // 8.4M elems (16.8 MB bf16)
    size_t wsz = (size_t)EMBED * EMBED;
    ushort_t* xb  = (ushort_t*)d_ws;
    ushort_t* Qb  = xb + tsz;
    ushort_t* Kb  = Qb + tsz;               // contiguous after Qb (merged GEMM relies on this)
    ushort_t* Vb  = Kb + tsz;
    ushort_t* Vt  = Vb + tsz;
    ushort_t* Wt0 = Vt + tsz;               // Wt0..Wt2 contiguous = concat QKV weights
    ushort_t* Wt3 = Wt0 + 3 * wsz;
    ushort_t* Ob  = xb;                     // alias: xb dead after QKV GEMM

    prep<<<5120, 256, 0, stream>>>(x, xb, Wq, Wk, Wv, Wo, Wt0);

    gemm_qkv<<<dim3(64, 24), 256, 0, stream>>>(xb, Wt0, bq, bk, bv, Qb, tsz);

    transpose_v<<<BATCH * HEADS * (SEQ / 64), 256, 0, stream>>>(Vb, Vt);
    flash_attn<<<1024, 512, 0, stream>>>(Qb, Kb, Vt, Ob);

    gemm_o<<<dim3(8, 64), 512, 0, stream>>>(Ob, Wt3, bo, out);
}